// Round 14
// baseline (2102.900 us; speedup 1.0000x reference)
//
#include <hip/hip_runtime.h>
#include <math.h>

typedef long long i64;
typedef short short8v __attribute__((ext_vector_type(8)));
typedef float float4v __attribute__((ext_vector_type(4)));

#define Hd 256
#define Bb 64
#define Tn 2047
#define LEAF0 1023
#define NTH 33538048LL   // B*T*H elements
#define GRID 512

__device__ __forceinline__ float frcp(float x){ return __builtin_amdgcn_rcpf(x); }
__device__ __forceinline__ float sigm(float x){ return frcp(1.0f+__expf(-x)); }
__device__ __forceinline__ float ftanh(float x){ return 1.0f - 2.0f*frcp(__expf(2.0f*x)+1.0f); }
__device__ __forceinline__ float bf2f(unsigned short s){
  union { unsigned u; float f; } v; v.u = ((unsigned)s)<<16; return v.f; }
__device__ __forceinline__ short f2bf(float f){
  union { float f; unsigned u; } v; v.f = f;
  unsigned r = v.u + 0x7FFF + ((v.u>>16)&1);
  return (short)(r>>16); }

#define GL2LDS(gp, lp) __builtin_amdgcn_global_load_lds( \
  (const __attribute__((address_space(1))) void*)(gp), \
  (__attribute__((address_space(3))) void*)(lp), 16, 0, 0)

// Device-scope grid barrier. Safe because all GRID blocks are co-resident
// (launch_bounds(512,4) => <=128 VGPR => 2 blocks/CU x 256 CU = 512).
// Counter is monotone; barrier m opens only after every block did m adds.
__device__ __forceinline__ void gbar(unsigned* cnt, int tid, unsigned target){
  __syncthreads();
  if (tid == 0){
    __threadfence();   // agent release: drains stores, writes back L2 (multi-XCD)
    __hip_atomic_fetch_add(cnt, 1u, __ATOMIC_RELEASE, __HIP_MEMORY_SCOPE_AGENT);
    while (__hip_atomic_load(cnt, __ATOMIC_ACQUIRE, __HIP_MEMORY_SCOPE_AGENT) < target)
      __builtin_amdgcn_s_sleep(2);
    __threadfence();   // agent acquire: invalidate caches before next phase reads
  }
  __syncthreads();
}

// ---------------------------------------------------------------------------
// One persistent kernel: prep -> leaf GEMM -> levels d=9..0, grid barriers
// between phases. GEMM tile: 128 rows x 64 hcols, 8 waves, A double-buffered
// via global_load_lds (16 KB LDS), B fragments in-loop from L2 registers.
// ---------------------------------------------------------------------------
__global__ __launch_bounds__(512, 4)
void fused_all(const float* __restrict__ W_iou, const float* __restrict__ U_iou,
               const float* __restrict__ U_f_w, const int* __restrict__ wordid,
               const float* __restrict__ emb, const float* __restrict__ b_iou,
               const float* __restrict__ U_f_b, const float* __restrict__ c0,
               short* __restrict__ Wt2I, short* __restrict__ Wt2L,
               short* __restrict__ hb, short* __restrict__ cbb,
               float* __restrict__ hOut, float* __restrict__ outRoot,
               unsigned* cnt){
  __shared__ __align__(16) short As[2][8*512];   // 16 KB
  const int tid = threadIdx.x;
  const int bid = blockIdx.x;
  const int lane = tid & 63, w = tid >> 6;
  const int wm = w >> 2, wg = w & 3;
  unsigned ep = 0;

  // ---- Phase 0: prep (weight pack + wemb overlay), grid-strided -----------
  for (i64 gidx = (i64)bid*512 + tid; gidx < 2203648LL; gidx += (i64)GRID*512){
    if (gidx < 81920){
      int t = (int)gidx;
      int ln = t & 63, rest = t >> 6;
      int nr = rest % 20; int rest2 = rest / 20;
      int kt = rest2 & 15, hhb = rest2 >> 4;
      int g = nr/5, strip = nr - g*5;
      int j = strip*256 + hhb*64 + g*16 + (ln&15);
      int k0 = kt*32 + (ln>>4)*8;
      const float* src = (j < 768) ? (U_iou + (i64)j*512 + k0)
                                   : (U_f_w + (i64)(j-768)*512 + k0);
      short* dst = Wt2I + (i64)t*8;
      #pragma unroll
      for (int e=0;e<8;e++) dst[e] = f2bf(src[e]);
    } else if (gidx < 106496){
      int t2 = (int)gidx - 81920;
      int ln = t2 & 63, rest = t2 >> 6;
      int nr = rest % 12; int rest2 = rest / 12;
      int kt = rest2 & 7, hhb = rest2 >> 3;
      int g = nr/3, strip = nr - g*3;
      int j = strip*256 + hhb*64 + g*16 + (ln&15);
      int k0 = kt*32 + (ln>>4)*8;
      const float* src = W_iou + (i64)j*256 + k0;
      short* dst = Wt2L + (i64)t2*8;
      #pragma unroll
      for (int e=0;e<8;e++) dst[e] = f2bf(src[e]);
    } else {
      int id = (int)(gidx - 106496);
      int row = id >> 5, q = id & 31;
      int b = row >> 10, j = row & 1023;
      i64 tb = (i64)b*Tn;
      const int* wid = wordid + (tb + LEAF0 + j)*5;
      float s[8];
      #pragma unroll
      for (int e=0;e<8;e++) s[e] = 0.f;
      #pragma unroll
      for (int l=0;l<5;l++){
        const float* er = emb + (i64)wid[l]*Hd + q*8;
        float4 v0 = *(const float4*)(er);
        float4 v1 = *(const float4*)(er+4);
        s[0]+=v0.x; s[1]+=v0.y; s[2]+=v0.z; s[3]+=v0.w;
        s[4]+=v1.x; s[5]+=v1.y; s[6]+=v1.z; s[7]+=v1.w;
      }
      short o[8];
      #pragma unroll
      for (int e=0;e<8;e++) o[e] = f2bf(s[e]);
      short* dst = (j < 1023) ? (hb + (tb + j)*Hd) : (cbb + tb*Hd);
      *(short8v*)(dst + q*8) = *(short8v*)o;
    }
  }
  gbar(cnt, tid, ++ep * GRID);

  // ---- Phase 1: leaf GEMM, 2048 tiles -------------------------------------
  for (int t = bid; t < 2048; t += GRID){
    const int hhb = t & 3;
    const int m0 = (t >> 2) * 128;

    const int rA = m0 + w*16 + (lane&15);
    const int bA = rA >> 10, jA = rA & 1023;
    const short* baseA = (jA < 1023) ? (hb + ((i64)bA*Tn + jA)*Hd)
                                     : (cbb + (i64)bA*Tn*Hd);
    const short* srcA = baseA + (lane>>4)*8;
    const short* gB0 = Wt2L + (i64)hhb*96*512 + (i64)(wg*3)*512 + lane*8;

    float4v acc[4][3];
    #pragma unroll
    for (int mr=0;mr<4;mr++)
      #pragma unroll
      for (int s=0;s<3;s++){ float4v z = {0.f,0.f,0.f,0.f}; acc[mr][s] = z; }

    GL2LDS(srcA, &As[0][w*512]);
    #pragma unroll 2
    for (int kt=0; kt<8; ++kt){
      __syncthreads();
      if (kt+1 < 8) GL2LDS(srcA + (kt+1)*32, &As[(kt+1)&1][w*512]);
      const short* bp = gB0 + (i64)kt*12*512;
      short8v bfr[3];
      #pragma unroll
      for (int s=0;s<3;s++) bfr[s] = *(const short8v*)(bp + (i64)s*512);
      #pragma unroll
      for (int mr=0;mr<4;mr++){
        short8v a = *(const short8v*)&As[kt&1][(wm*4+mr)*512 + lane*8];
        #pragma unroll
        for (int s=0;s<3;s++)
          acc[mr][s] = __builtin_amdgcn_mfma_f32_16x16x32_bf16(a, bfr[s], acc[mr][s], 0, 0, 0);
      }
    }
    __syncthreads();   // protect As before next tile's prologue write

    const int hcol = hhb*64 + wg*16 + (lane&15);
    const float bi = b_iou[hcol], bo = b_iou[256+hcol], bu = b_iou[512+hcol];
    #pragma unroll
    for (int mr=0;mr<4;mr++){
      const int mgb = m0 + wm*64 + mr*16 + ((lane>>4)<<2);
      #pragma unroll
      for (int r=0;r<4;r++){
        const int m = mgb + r;
        const int b = m >> 10, j = m & 1023;
        const i64 n = (i64)b*Tn + LEAF0 + j;
        const float i_ = acc[mr][0][r] + bi;
        const float o_ = acc[mr][1][r] + bo;
        const float u_ = acc[mr][2][r] + bu;
        const float cn = sigm(i_)*ftanh(u_) + c0[n*Hd + hcol];
        const float hv = sigm(o_)*ftanh(cn);
        cbb[n*Hd + hcol] = f2bf(cn);
        hb[n*Hd + hcol]  = f2bf(hv);
        hOut[n*Hd + hcol] = hv;
      }
    }
  }
  gbar(cnt, tid, ++ep * GRID);

  // ---- Phase 2: levels d=9..0 ---------------------------------------------
  for (int d = 9; d >= 0; --d){
    const int Mtot = Bb << d;
    const int s0 = (1<<d) - 1, e0 = (2<<d) - 1;
    const int nm1 = (1<<d) - 1;
    const int ntiles = ((Mtot + 127) >> 7) * 4;
    for (int t = bid; t < ntiles; t += GRID){
      const int hhb = t & 3;
      const int m0 = (t >> 2) * 128;

      int rA = m0 + w*16 + (lane&15); if (rA >= Mtot) rA = Mtot-1;
      const int bA = rA >> d, jA = rA & nm1;
      const short* srcA = hb + ((i64)bA*Tn + e0)*Hd + (i64)jA*512 + (lane>>4)*8;
      const short* gB0 = Wt2I + (i64)hhb*320*512 + (i64)(wg*5)*512 + lane*8;

      float4v acc[4][5];
      #pragma unroll
      for (int mr=0;mr<4;mr++)
        #pragma unroll
        for (int s=0;s<5;s++){ float4v z = {0.f,0.f,0.f,0.f}; acc[mr][s] = z; }

      GL2LDS(srcA, &As[0][w*512]);
      #pragma unroll 2
      for (int kt=0; kt<16; ++kt){
        __syncthreads();
        if (kt+1 < 16) GL2LDS(srcA + (kt+1)*32, &As[(kt+1)&1][w*512]);
        const short* bp = gB0 + (i64)kt*20*512;
        short8v bfr[5];
        #pragma unroll
        for (int s=0;s<5;s++) bfr[s] = *(const short8v*)(bp + (i64)s*512);
        #pragma unroll
        for (int mr=0;mr<4;mr++){
          short8v a = *(const short8v*)&As[kt&1][(wm*4+mr)*512 + lane*8];
          #pragma unroll
          for (int s=0;s<5;s++)
            acc[mr][s] = __builtin_amdgcn_mfma_f32_16x16x32_bf16(a, bfr[s], acc[mr][s], 0, 0, 0);
        }
      }
      __syncthreads();   // protect As before next tile's prologue write

      const int hcol = hhb*64 + wg*16 + (lane&15);
      const float bi = b_iou[hcol], bo = b_iou[256+hcol], bu = b_iou[512+hcol];
      const float bfl = U_f_b[hcol], bfr2 = U_f_b[256+hcol];
      #pragma unroll
      for (int mr=0;mr<4;mr++){
        const int mgb = m0 + wm*64 + mr*16 + ((lane>>4)<<2);
        #pragma unroll
        for (int r=0;r<4;r++){
          const int m = mgb + r;
          if (m < Mtot){
            const int b = m >> d, j = m & nm1;
            const i64 base = (i64)b*Tn;
            const i64 cidx = (base + e0 + 2*j)*Hd + hcol;
            const float cl = bf2f((unsigned short)cbb[cidx]);
            const float cr = bf2f((unsigned short)cbb[cidx + Hd]);
            const float i_ = acc[mr][0][r]+bi, o_ = acc[mr][1][r]+bo, u_ = acc[mr][2][r]+bu;
            const float fl = acc[mr][3][r]+bfl, fr = acc[mr][4][r]+bfr2;
            const float cn = sigm(i_)*ftanh(u_) + sigm(fl)*cl + sigm(fr)*cr;
            const float hv = sigm(o_)*ftanh(cn);
            const i64 oidx = (base + s0 + j)*Hd + hcol;
            cbb[oidx] = f2bf(cn);
            hb[oidx]  = f2bf(hv);
            hOut[oidx] = hv;
            if (s0 == 0){
              outRoot[b*Hd + hcol] = hv;
              outRoot[Bb*Hd + b*Hd + hcol] = cn;
            }
          }
        }
      }
    }
    if (d > 0) gbar(cnt, tid, ++ep * GRID);
  }
}

extern "C" void kernel_launch(void* const* d_in, const int* in_sizes, int n_in,
                              void* d_out, int out_size, void* d_ws, size_t ws_size,
                              hipStream_t stream){
  const int*   wordid = (const int*)  d_in[0];
  const float* c0     = (const float*)d_in[3];
  const float* emb    = (const float*)d_in[6];
  const float* W_iou  = (const float*)d_in[7];
  const float* U_iou  = (const float*)d_in[8];
  const float* b_iou  = (const float*)d_in[9];
  const float* U_f_w  = (const float*)d_in[10];
  const float* U_f_b  = (const float*)d_in[11];

  float* hOut    = (float*)d_out;            // (B,T,H) fp32
  float* outRoot = hOut + NTH;               // root_h then root_c
  short* cbb  = (short*)d_ws;                // c bf16; root rows hold wemb overlay
  short* hb   = cbb + NTH;                   // h bf16; internal rows hold wemb overlay pre-leaf
  short* Wt2I = hb + NTH;                    // 655360 shorts
  short* Wt2L = Wt2I + 655360;               // 196608 shorts
  unsigned* cnt = (unsigned*)(Wt2L + 196608);

  hipMemsetAsync(cnt, 0, 4, stream);
  hipLaunchKernelGGL(fused_all, dim3(GRID), dim3(512), 0, stream,
                     W_iou, U_iou, U_f_w, wordid, emb, b_iou, U_f_b, c0,
                     Wt2I, Wt2L, hb, cbb, hOut, outRoot, cnt);
}

// Round 15
// 383.350 us; speedup vs baseline: 5.4856x; 5.4856x over previous
//
#include <hip/hip_runtime.h>
#include <math.h>

typedef long long i64;
typedef short short8v __attribute__((ext_vector_type(8)));
typedef float float4v __attribute__((ext_vector_type(4)));

#define Hd 256
#define Bb 64
#define Tn 2047
#define LEAF0 1023
#define NTH 33538048LL   // B*T*H elements

__device__ __forceinline__ float frcp(float x){ return __builtin_amdgcn_rcpf(x); }
__device__ __forceinline__ float sigm(float x){ return frcp(1.0f+__expf(-x)); }
__device__ __forceinline__ float ftanh(float x){ return 1.0f - 2.0f*frcp(__expf(2.0f*x)+1.0f); }
__device__ __forceinline__ float bf2f(unsigned short s){
  union { unsigned u; float f; } v; v.u = ((unsigned)s)<<16; return v.f; }
__device__ __forceinline__ short f2bf(float f){
  union { float f; unsigned u; } v; v.f = f;
  unsigned r = v.u + 0x7FFF + ((v.u>>16)&1);
  return (short)(r>>16); }

#define GL2LDS(gp, lp) __builtin_amdgcn_global_load_lds( \
  (const __attribute__((address_space(1))) void*)(gp), \
  (__attribute__((address_space(3))) void*)(lp), 16, 0, 0)

// ---------------------------------------------------------------------------
// prep: blocks [0,320) pack Wt2I; [320,416) pack Wt2L; [416,8608) wemb overlay.
// wemb: leaf j<1023 -> hb internal row (b*Tn+j); j==1023 -> cbb root row.
// ---------------------------------------------------------------------------
__global__ __launch_bounds__(256)
void prep_kernel(const float* __restrict__ W_iou, const float* __restrict__ U_iou,
                 const float* __restrict__ U_f_w,
                 short* __restrict__ Wt2I, short* __restrict__ Wt2L,
                 const int* __restrict__ wordid, const float* __restrict__ emb,
                 short* __restrict__ hb, short* __restrict__ cbb){
  if (blockIdx.x < 320){
    int t = blockIdx.x*256 + threadIdx.x;
    int lane = t & 63, rest = t >> 6;
    int nr = rest % 20; int rest2 = rest / 20;
    int kt = rest2 & 15, hhb = rest2 >> 4;
    int g = nr/5, strip = nr - g*5;
    int j = strip*256 + hhb*64 + g*16 + (lane&15);
    int k0 = kt*32 + (lane>>4)*8;
    const float* src = (j < 768) ? (U_iou + (i64)j*512 + k0)
                                 : (U_f_w + (i64)(j-768)*512 + k0);
    short* dst = Wt2I + (i64)t*8;
    #pragma unroll
    for (int e=0;e<8;e++) dst[e] = f2bf(src[e]);
  } else if (blockIdx.x < 416){
    int t2 = (blockIdx.x-320)*256 + threadIdx.x;
    int lane = t2 & 63, rest = t2 >> 6;
    int nr = rest % 12; int rest2 = rest / 12;
    int kt = rest2 & 7, hhb = rest2 >> 3;
    int g = nr/3, strip = nr - g*3;
    int j = strip*256 + hhb*64 + g*16 + (lane&15);
    int k0 = kt*32 + (lane>>4)*8;
    const float* src = W_iou + (i64)j*256 + k0;
    short* dst = Wt2L + (i64)t2*8;
    #pragma unroll
    for (int e=0;e<8;e++) dst[e] = f2bf(src[e]);
  } else {
    int id = (blockIdx.x-416)*256 + threadIdx.x;
    int row = id >> 5, q = id & 31;
    int b = row >> 10, j = row & 1023;
    i64 tb = (i64)b*Tn;
    const int* wid = wordid + (tb + LEAF0 + j)*5;
    float s[8];
    #pragma unroll
    for (int e=0;e<8;e++) s[e] = 0.f;
    #pragma unroll
    for (int l=0;l<5;l++){
      const float* er = emb + (i64)wid[l]*Hd + q*8;
      float4 v0 = *(const float4*)(er);
      float4 v1 = *(const float4*)(er+4);
      s[0]+=v0.x; s[1]+=v0.y; s[2]+=v0.z; s[3]+=v0.w;
      s[4]+=v1.x; s[5]+=v1.y; s[6]+=v1.z; s[7]+=v1.w;
    }
    short o[8];
    #pragma unroll
    for (int e=0;e<8;e++) o[e] = f2bf(s[e]);
    short* dst = (j < 1023) ? (hb + (tb + j)*Hd) : (cbb + tb*Hd);
    *(short8v*)(dst + q*8) = *(short8v*)o;
  }
}

// ---------------------------------------------------------------------------
// Leaf GEMM (R7 verbatim): block 128 rows x 64 hcols x {i,o,u}. A: ring-5 LDS,
// 3 ahead; B: regs triple-buffered, 2 ahead; exact counted vmcnt.
// ---------------------------------------------------------------------------
#define LEAF_ITER(KT, VM, BU, BL)                                            \
  {                                                                          \
    if ((KT)+2 < 8){                                                         \
      const short* bp = wbB + (i64)((KT)+2)*12*512;                          \
      _Pragma("unroll")                                                      \
      for (int s=0;s<3;s++) BL[s] = *(const short8v*)(bp + (i64)s*512);      \
    }                                                                        \
    asm volatile("" ::: "memory");                                           \
    if ((KT)+3 < 8) GL2LDS(srcA + ((KT)+3)*32, &As[((KT)+3)%5][w*512]);      \
    asm volatile("s_waitcnt vmcnt(" #VM ")" ::: "memory");                   \
    __builtin_amdgcn_s_barrier();                                            \
    asm volatile("" ::: "memory");                                           \
    short8v afr[4];                                                          \
    _Pragma("unroll")                                                        \
    for (int mr=0;mr<4;mr++)                                                 \
      afr[mr] = *(const short8v*)&As[(KT)%5][(wm*4+mr)*512 + lane*8];        \
    _Pragma("unroll")                                                        \
    for (int mr=0;mr<4;mr++)                                                 \
      _Pragma("unroll")                                                      \
      for (int s=0;s<3;s++)                                                  \
        acc[mr][s] = __builtin_amdgcn_mfma_f32_16x16x32_bf16(afr[mr], BU[s], acc[mr][s], 0, 0, 0); \
    asm volatile("s_waitcnt lgkmcnt(0)" ::: "memory");                       \
  }

__global__ __launch_bounds__(512)
void leaf_gemm(const short* __restrict__ hb, const short* __restrict__ cbb,
               const short* __restrict__ WB,
               const float* __restrict__ b_iou, const float* __restrict__ c0,
               float* __restrict__ hOut, short* __restrict__ hbOut,
               short* __restrict__ cbbOut){
  __shared__ __align__(16) short As[5][8*512];   // 40 KB
  const int tid = threadIdx.x;
  const int lane = tid & 63, w = tid >> 6;
  const int wm = w >> 2, wg = w & 3;
  const int m0 = blockIdx.x*128;
  const int hhb = blockIdx.y;

  const int rA = m0 + w*16 + (lane&15);
  const int bA = rA >> 10, jA = rA & 1023;
  const short* baseA = (jA < 1023) ? (hb + ((i64)bA*Tn + jA)*Hd)
                                   : (cbb + (i64)bA*Tn*Hd);
  const short* srcA = baseA + (lane>>4)*8;
  const short* wbB = WB + (i64)hhb*96*512 + (i64)(wg*3)*512 + lane*8;

  float4v acc[4][3];
  #pragma unroll
  for (int mr=0;mr<4;mr++)
    #pragma unroll
    for (int s=0;s<3;s++){ float4v z = {0.f,0.f,0.f,0.f}; acc[mr][s] = z; }

  short8v b0[3], b1[3], b2[3];
  #pragma unroll
  for (int s=0;s<3;s++) b0[s] = *(const short8v*)(wbB + (i64)s*512);
  asm volatile("" ::: "memory");
  GL2LDS(srcA, &As[0][w*512]);
  GL2LDS(srcA + 32, &As[1][w*512]);
  GL2LDS(srcA + 64, &As[2][w*512]);
  asm volatile("" ::: "memory");
  #pragma unroll
  for (int s=0;s<3;s++) b1[s] = *(const short8v*)(wbB + (i64)(12+s)*512);
  asm volatile("" ::: "memory");

  LEAF_ITER(0,9,b0,b2)  LEAF_ITER(1,8,b1,b0)
  LEAF_ITER(2,9,b2,b1)  LEAF_ITER(3,9,b0,b2)
  LEAF_ITER(4,9,b1,b0)  LEAF_ITER(5,8,b2,b1)
  LEAF_ITER(6,4,b0,b2)  LEAF_ITER(7,0,b1,b0)

  const int hcol = hhb*64 + wg*16 + (lane&15);
  const float bi = b_iou[hcol], bo = b_iou[256+hcol], bu = b_iou[512+hcol];
  #pragma unroll
  for (int mr=0;mr<4;mr++){
    const int mgb = m0 + wm*64 + mr*16 + ((lane>>4)<<2);
    #pragma unroll
    for (int r=0;r<4;r++){
      const int m = mgb + r;
      const int b = m >> 10, j = m & 1023;
      const i64 n = (i64)b*Tn + LEAF0 + j;
      const float i_ = acc[mr][0][r] + bi;
      const float o_ = acc[mr][1][r] + bo;
      const float u_ = acc[mr][2][r] + bu;
      const float cn = sigm(i_)*ftanh(u_) + c0[n*Hd + hcol];
      const float hv = sigm(o_)*ftanh(cn);
      cbbOut[n*Hd + hcol] = f2bf(cn);
      hbOut[n*Hd + hcol]  = f2bf(hv);
      hOut[n*Hd + hcol] = hv;
    }
  }
}

// ---------------------------------------------------------------------------
// Internal level d=9..6 (R7 verbatim): block 128 rows x 64 hcols x
// {i,o,u,fl,fr}. A: ring-5 LDS 3 ahead; B: regs tbuf 2 ahead; counted vmcnt.
// ---------------------------------------------------------------------------
#define LVL_ITER(KT, VM, BU, BL)                                             \
  {                                                                          \
    if ((KT)+2 < 16){                                                        \
      const short* bp = wbB + (i64)((KT)+2)*20*512;                          \
      _Pragma("unroll")                                                      \
      for (int s=0;s<5;s++) BL[s] = *(const short8v*)(bp + (i64)s*512);      \
    }                                                                        \
    asm volatile("" ::: "memory");                                           \
    if ((KT)+3 < 16) GL2LDS(srcA + ((KT)+3)*32, &As[((KT)+3)%5][w*512]);     \
    asm volatile("s_waitcnt vmcnt(" #VM ")" ::: "memory");                   \
    __builtin_amdgcn_s_barrier();                                            \
    asm volatile("" ::: "memory");                                           \
    short8v afr[4];                                                          \
    _Pragma("unroll")                                                        \
    for (int mr=0;mr<4;mr++)                                                 \
      afr[mr] = *(const short8v*)&As[(KT)%5][(wm*4+mr)*512 + lane*8];        \
    _Pragma("unroll")                                                        \
    for (int mr=0;mr<4;mr++)                                                 \
      _Pragma("unroll")                                                      \
      for (int s=0;s<5;s++)                                                  \
        acc[mr][s] = __builtin_amdgcn_mfma_f32_16x16x32_bf16(afr[mr], BU[s], acc[mr][s], 0, 0, 0); \
    asm volatile("s_waitcnt lgkmcnt(0)" ::: "memory");                       \
  }

__global__ __launch_bounds__(512)
void level_gemm(const short* __restrict__ WB,
                const float* __restrict__ b_iou, const float* __restrict__ U_f_b,
                float* __restrict__ hOut, short* __restrict__ hb, short* __restrict__ cbb,
                int s0, int e0, int logn){
  __shared__ __align__(16) short As[5][8*512];   // 40 KB
  const int tid = threadIdx.x;
  const int lane = tid & 63, w = tid >> 6;
  const int wm = w >> 2, wg = w & 3;
  const int m0 = blockIdx.x*128;
  const int hhb = blockIdx.y;
  const int nm1 = (1<<logn)-1;

  const int rA = m0 + w*16 + (lane&15);
  const int bA = rA >> logn, jA = rA & nm1;
  const short* srcA = hb + ((i64)bA*Tn + e0)*Hd + (i64)jA*512 + (lane>>4)*8;
  const short* wbB = WB + (i64)hhb*320*512 + (i64)(wg*5)*512 + lane*8;

  float4v acc[4][5];
  #pragma unroll
  for (int mr=0;mr<4;mr++)
    #pragma unroll
    for (int s=0;s<5;s++){ float4v z = {0.f,0.f,0.f,0.f}; acc[mr][s] = z; }

  short8v b0[5], b1[5], b2[5];
  #pragma unroll
  for (int s=0;s<5;s++) b0[s] = *(const short8v*)(wbB + (i64)s*512);
  asm volatile("" ::: "memory");
  GL2LDS(srcA, &As[0][w*512]);
  GL2LDS(srcA + 32, &As[1][w*512]);
  GL2LDS(srcA + 64, &As[2][w*512]);
  asm volatile("" ::: "memory");
  #pragma unroll
  for (int s=0;s<5;s++) b1[s] = *(const short8v*)(wbB + (i64)(20+s)*512);
  asm volatile("" ::: "memory");

  LVL_ITER( 0,13,b0,b2)  LVL_ITER( 1,12,b1,b0)  LVL_ITER( 2,13,b2,b1)
  LVL_ITER( 3,13,b0,b2)  LVL_ITER( 4,13,b1,b0)  LVL_ITER( 5,13,b2,b1)
  LVL_ITER( 6,13,b0,b2)  LVL_ITER( 7,13,b1,b0)  LVL_ITER( 8,13,b2,b1)
  LVL_ITER( 9,13,b0,b2)  LVL_ITER(10,13,b1,b0)  LVL_ITER(11,13,b2,b1)
  LVL_ITER(12,13,b0,b2)  LVL_ITER(13,12,b1,b0)  LVL_ITER(14, 6,b2,b1)
  LVL_ITER(15, 0,b0,b2)

  const int hcol = hhb*64 + wg*16 + (lane&15);
  const float bi = b_iou[hcol], bo = b_iou[256+hcol], bu = b_iou[512+hcol];
  const float bfl = U_f_b[hcol], bfr2 = U_f_b[256+hcol];
  #pragma unroll
  for (int mr=0;mr<4;mr++){
    const int mgb = m0 + wm*64 + mr*16 + ((lane>>4)<<2);
    #pragma unroll
    for (int r=0;r<4;r++){
      const int m = mgb + r;
      const int b = m >> logn, j = m & nm1;
      const i64 base = (i64)b*Tn;
      const i64 cidx = (base + e0 + 2*j)*Hd + hcol;
      const float cl = bf2f((unsigned short)cbb[cidx]);
      const float cr = bf2f((unsigned short)cbb[cidx + Hd]);
      const float i_ = acc[mr][0][r]+bi, o_ = acc[mr][1][r]+bo, u_ = acc[mr][2][r]+bu;
      const float fl = acc[mr][3][r]+bfl, fr = acc[mr][4][r]+bfr2;
      const float cn = sigm(i_)*ftanh(u_) + sigm(fl)*cl + sigm(fr)*cr;
      const float hv = sigm(o_)*ftanh(cn);
      const i64 oidx = (base + s0 + j)*Hd + hcol;
      cbb[oidx] = f2bf(cn);
      hb[oidx]  = f2bf(hv);
      hOut[oidx] = hv;
    }
  }
}

// ---------------------------------------------------------------------------
// Fused small levels d=5..0 (R9 v2 verbatim): one block per tree, 8 waves all
// busy; wave = 2 colgroups x 5 strips; children h/c ping-pong in XOR-swizzled
// LDS; B from L2; 1 barrier/level.
// ---------------------------------------------------------------------------
__global__ __launch_bounds__(512)
void tree_fused(const short* __restrict__ WB, const float* __restrict__ b_iou,
                const float* __restrict__ U_f_b, float* __restrict__ hOut,
                const short* __restrict__ hb, const short* __restrict__ cbb,
                float* __restrict__ outRoot){
  __shared__ __align__(16) char BUF[96*1024];
  char* bAh = BUF;
  char* bAc = BUF + 32*1024;
  char* bBh = BUF + 64*1024;
  char* bBc = BUF + 80*1024;
  const int tid = threadIdx.x;
  const int lane = tid & 63, w = tid >> 6;
  const int hhb = w >> 1;
  const int g0 = (w & 1) * 2;
  const int b = blockIdx.x;
  const i64 tb = (i64)b*Tn;

  #pragma unroll
  for (int p=0;p<4;p++){
    int idx = p*512 + tid;
    int row = idx >> 5, ch = idx & 31;
    int off = row*512 + ((ch*16) ^ (((row>>1)&7)<<4));
    *(short8v*)(bAh + off) = *(const short8v*)(hb  + (tb + 63 + row)*Hd + ch*8);
    *(short8v*)(bAc + off) = *(const short8v*)(cbb + (tb + 63 + row)*Hd + ch*8);
  }
  __syncthreads();

  char* inH = bAh; char* inC = bAc; char* outH = bBh; char* outC = bBc;

  for (int d = 5; d >= 0; --d){
    const int M = 1<<d, s0v = M-1;
    const int nmf = (d == 5) ? 2 : 1;
    for (int mf = 0; mf < nmf; ++mf){
      const int j = mf*16 + (lane&15);
      const int qq = lane >> 4;
      float4v acc[2][5];
      #pragma unroll
      for (int c=0;c<2;c++)
        #pragma unroll
        for (int s=0;s<5;s++){ float4v z = {0.f,0.f,0.f,0.f}; acc[c][s] = z; }
      #pragma unroll 2
      for (int kt=0; kt<16; ++kt){
        const int crow = 2*j + (kt>>3);
        const int ccolB = ((kt&7)*32 + qq*8)*2;
        short8v a = *(const short8v*)(inH + crow*512 + (ccolB ^ (((crow>>1)&7)<<4)));
        const short* bp = WB + (i64)hhb*163840 + (i64)kt*10240 + (i64)lane*8;
        #pragma unroll
        for (int c=0;c<2;c++)
          #pragma unroll
          for (int s=0;s<5;s++){
            short8v bb = *(const short8v*)(bp + (i64)((g0+c)*5+s)*512);
            acc[c][s] = __builtin_amdgcn_mfma_f32_16x16x32_bf16(a, bb, acc[c][s], 0, 0, 0);
          }
      }
      #pragma unroll
      for (int c=0;c<2;c++){
        const int hcol = hhb*64 + (g0+c)*16 + (lane&15);
        const float bi = b_iou[hcol], bo = b_iou[256+hcol], bu = b_iou[512+hcol];
        const float bfl = U_f_b[hcol], bfr2 = U_f_b[256+hcol];
        #pragma unroll
        for (int r=0;r<4;r++){
          const int row = mf*16 + qq*4 + r;
          if (row < M){
            const int cxor = (hcol*2) ^ ((row&7)<<4);
            const float cl = bf2f(*(const unsigned short*)(inC + row*1024 + cxor));
            const float cr = bf2f(*(const unsigned short*)(inC + row*1024 + 512 + cxor));
            const float i_ = acc[c][0][r]+bi, o_ = acc[c][1][r]+bo, u_ = acc[c][2][r]+bu;
            const float fl = acc[c][3][r]+bfl, fr = acc[c][4][r]+bfr2;
            const float cn = sigm(i_)*ftanh(u_) + sigm(fl)*cl + sigm(fr)*cr;
            const float hv = sigm(o_)*ftanh(cn);
            const int woff = row*512 + ((hcol*2) ^ (((row>>1)&7)<<4));
            *(short*)(outH + woff) = f2bf(hv);
            *(short*)(outC + woff) = f2bf(cn);
            hOut[(tb + s0v + row)*Hd + hcol] = hv;
            if (d == 0){
              outRoot[b*Hd + hcol] = hv;
              outRoot[Bb*Hd + b*Hd + hcol] = cn;
            }
          }
        }
      }
    }
    __syncthreads();
    char* t;
    t = inH; inH = outH; outH = t;
    t = inC; inC = outC; outC = t;
  }
}

extern "C" void kernel_launch(void* const* d_in, const int* in_sizes, int n_in,
                              void* d_out, int out_size, void* d_ws, size_t ws_size,
                              hipStream_t stream){
  const int*   wordid = (const int*)  d_in[0];
  const float* c0     = (const float*)d_in[3];
  const float* emb    = (const float*)d_in[6];
  const float* W_iou  = (const float*)d_in[7];
  const float* U_iou  = (const float*)d_in[8];
  const float* b_iou  = (const float*)d_in[9];
  const float* U_f_w  = (const float*)d_in[10];
  const float* U_f_b  = (const float*)d_in[11];

  float* hOut    = (float*)d_out;            // (B,T,H) fp32
  float* outRoot = hOut + NTH;               // root_h then root_c
  short* cbb  = (short*)d_ws;                // c bf16; root rows hold wemb overlay
  short* hb   = cbb + NTH;                   // h bf16; internal rows hold wemb overlay pre-leaf
  short* Wt2I = hb + NTH;                    // 655360 shorts
  short* Wt2L = Wt2I + 655360;               // 196608 shorts

  hipLaunchKernelGGL(prep_kernel, dim3(8608), dim3(256), 0, stream,
                     W_iou, U_iou, U_f_w, Wt2I, Wt2L, wordid, emb, hb, cbb);
  hipLaunchKernelGGL(leaf_gemm, dim3(512,4), dim3(512), 0, stream,
                     hb, cbb, Wt2L, b_iou, c0, hOut, hb, cbb);
  for (int d = 9; d >= 6; --d){
    const int n = 1<<d, s = n-1, e = 2*n-1;
    const int bm = (64*n + 127)/128;
    hipLaunchKernelGGL(level_gemm, dim3(bm,4), dim3(512), 0, stream,
                       Wt2I, b_iou, U_f_b, hOut, hb, cbb, s, e, d);
  }
  hipLaunchKernelGGL(tree_fused, dim3(64), dim3(512), 0, stream,
                     Wt2I, b_iou, U_f_b, hOut, hb, cbb, outRoot);
}